// Round 2
// baseline (136.910 us; speedup 1.0000x reference)
//
#include <hip/hip_runtime.h>

#define IC    128
#define OC    128
#define LMAX  80
#define NL    81          // LMAX+1 degrees
#define PTOT  6561        // (L+1)^2 positions
#define NCPT  17
#define BSTR  (IC*PTOT)   // x batch stride (839808)
#define NBLK  1681        // sum over l of ceil(16*(2l+1)/64) = 41^2

typedef short short8 __attribute__((ext_vector_type(8)));
typedef float f32x4  __attribute__((ext_vector_type(4)));

__device__ __forceinline__ unsigned short f2bf(float x) {
    unsigned u = __float_as_uint(x);
    return (unsigned short)((u + 0x7FFFu + ((u >> 16) & 1u)) >> 16);
}

// One block per output channel o: stage anchors w[:, o, :] in LDS, lerp to
// per-degree weights, write Wt[l][o][i] (bf16) coalesced along i.
__global__ __launch_bounds__(256) void shconv_prep(const float* __restrict__ w,
                                                   unsigned short* __restrict__ Wt) {
    const int o = blockIdx.x;
    const int t = threadIdx.x;
    __shared__ float ws[IC * NCPT];          // 2176 floats, laid out [i][s]
    for (int e = t; e < IC * NCPT; e += 256) {
        int i = e / NCPT;
        int s = e - i * NCPT;
        ws[e] = w[i * (OC * NCPT) + o * NCPT + s];
    }
    __syncthreads();
    for (int f = t; f < NL * IC; f += 256) {
        int l = f >> 7;
        int i = f & 127;
        int s; float fr;
        if (l < 75) { s = l / 5;  fr = (float)(l - s * 5) / 5.0f; }
        else        { s = 15;     fr = (float)(l - 75) / 5.0f;    }
        float v = (1.0f - fr) * ws[i * NCPT + s] + fr * ws[i * NCPT + s + 1];
        Wt[l * (OC * IC) + o * IC + i] = f2bf(v);
    }
}

// Block = (degree l, 64-column chunk). Columns enumerate (b, p) pairs of the
// segment [l^2, (l+1)^2) across all 16 batches. W_l staged in LDS (bf16,
// rows padded to 272B). Each wave owns a distinct 16-column group; B-frags
// loaded straight from global x (coalesced along p), converted to bf16.
__global__ __launch_bounds__(256) void shconv_main(const float* __restrict__ x,
                                                   const unsigned short* __restrict__ Wt,
                                                   float* __restrict__ out) {
    __shared__ __align__(16) unsigned short Wl[128 * 136];   // 34816 B

    const int tid = threadIdx.x;

    // blockIdx -> (l, chunk):  cum-chunks C(2m)=m(m+1), C(2m+1)=(m+1)^2
    int q = blockIdx.x;
    int t = (int)sqrtf((float)q);
    while (t * t > q) --t;
    while ((t + 1) * (t + 1) <= q) ++t;
    int l, chunk;
    if (q < t * (t + 1)) { l = 2 * t - 1; chunk = q - t * t; }
    else                 { l = 2 * t;     chunk = q - t * (t + 1); }

    const int len  = 2 * l + 1;
    const int cols = 16 * len;
    const int c0   = chunk * 64;

    // ---- stage W_l (layout [o][i], bf16) into LDS ----
    {
        const unsigned short* src = Wt + l * (OC * IC);
        #pragma unroll
        for (int it = 0; it < 8; ++it) {
            int idx = tid + it * 256;            // 0..2047, one 16B chunk each
            int o   = idx >> 4;
            int seg = idx & 15;
            *(uint4*)(&Wl[o * 136 + seg * 8]) = *(const uint4*)(src + idx * 8);
        }
    }
    __syncthreads();

    const int lane = tid & 63;
    const int wave = tid >> 6;
    const int m    = lane & 15;   // MFMA n-col / A-row selector
    const int g    = lane >> 4;   // k-group

    int c = c0 + wave * 16 + m;
    const bool valid = (c < cols);
    int ccl = valid ? c : (cols - 1);
    int b   = (int)((unsigned)ccl / (unsigned)len);
    int pp  = ccl - b * len;
    int p   = l * l + pp;

    const float* xg = x + (size_t)b * BSTR + (size_t)(g * 8) * PTOT + p;

    // load this lane's 32 K-values of x (coalesced along p across lanes)
    float xv[32];
    #pragma unroll
    for (int kk = 0; kk < 4; ++kk)
        #pragma unroll
        for (int j = 0; j < 8; ++j)
            xv[kk * 8 + j] = xg[(kk * 32 + j) * PTOT];

    short8 bfr[4];
    #pragma unroll
    for (int kk = 0; kk < 4; ++kk)
        #pragma unroll
        for (int j = 0; j < 8; ++j)
            bfr[kk][j] = (short)f2bf(xv[kk * 8 + j]);

    f32x4 acc[8];
    #pragma unroll
    for (int of = 0; of < 8; ++of) acc[of] = (f32x4){0.f, 0.f, 0.f, 0.f};

    #pragma unroll
    for (int kk = 0; kk < 4; ++kk) {
        #pragma unroll
        for (int of = 0; of < 8; ++of) {
            short8 af = *(const short8*)(&Wl[(of * 16 + m) * 136 + kk * 32 + g * 8]);
            acc[of] = __builtin_amdgcn_mfma_f32_16x16x32_bf16(af, bfr[kk], acc[of], 0, 0, 0);
        }
    }

    if (valid) {
        float* ob = out + (size_t)b * (OC * PTOT) + p;
        #pragma unroll
        for (int of = 0; of < 8; ++of)
            #pragma unroll
            for (int j = 0; j < 4; ++j)
                ob[(of * 16 + g * 4 + j) * PTOT] = acc[of][j];
    }
}

extern "C" void kernel_launch(void* const* d_in, const int* in_sizes, int n_in,
                              void* d_out, int out_size, void* d_ws, size_t ws_size,
                              hipStream_t stream) {
    const float* x = (const float*)d_in[0];
    const float* w = (const float*)d_in[1];
    unsigned short* Wt = (unsigned short*)d_ws;     // 81*128*128 bf16 = 2.65 MB
    float* out = (float*)d_out;

    shconv_prep<<<dim3(OC), dim3(256), 0, stream>>>(w, Wt);
    shconv_main<<<dim3(NBLK), dim3(256), 0, stream>>>(x, Wt, out);
}